// Round 10
// baseline (854.920 us; speedup 1.0000x reference)
//
#include <hip/hip_runtime.h>
#include <stdint.h>

#define T_STEPS 128
#define BATCH   64
#define EMBED   256
#define HIDDEN  512
#define VOCAB   10000
#define M_ROWS  (T_STEPS*BATCH)   // 8192
#define NGATE   (4*HIDDEN)        // 2048
#define NBLK    32                // lstm worker blocks
#define NLAUNCH 256               // total cooperative blocks
#define NTILE_N 125               // 10000/80

typedef __attribute__((ext_vector_type(2))) float  f32x2;
typedef __attribute__((ext_vector_type(4))) float  f32x4;
typedef __attribute__((ext_vector_type(4))) int    i32x4;
typedef __attribute__((ext_vector_type(8))) __bf16 bf16x8;

static __device__ __forceinline__ unsigned short f32_to_bf16(float f) {
    union { float f; uint32_t u; } v; v.f = f;
    uint32_t u = v.u;
    return (unsigned short)((u + 0x7FFFu + ((u >> 16) & 1u)) >> 16);  // RNE
}
static __device__ __forceinline__ float sigf(float x) {
    return 1.f / (1.f + __expf(-x));
}
static __device__ __forceinline__ float tanhfast(float x) {
    float e = __expf(2.f * fminf(fmaxf(x, -15.f), 15.f));
    return (e - 1.f) / (e + 1.f);
}
static __device__ __forceinline__ void cell2(
    float pi0, float pi1, float pf0, float pf1, float pg0, float pg1,
    float po0, float po1, float& c0, float& c1, float& h0, float& h1) {
    float i0 = sigf(pi0), i1 = sigf(pi1);
    float f0 = sigf(pf0), f1 = sigf(pf1);
    float g0 = tanhfast(pg0), g1 = tanhfast(pg1);
    float o0 = sigf(po0), o1 = sigf(po1);
    c0 = f0 * c0 + i0 * g0;
    c1 = f1 * c1 + i1 * g1;
    h0 = o0 * tanhfast(c0);
    h1 = o1 * tanhfast(c1);
}

// IC-coherent (bypass L1+L2) primitives — the verified cross-XCD path.
static __device__ __forceinline__ i32x4 ld16ic(const void* p) {
    i32x4 r; asm volatile("global_load_dwordx4 %0, %1, off sc0 sc1" : "=v"(r) : "v"(p)); return r;
}
static __device__ __forceinline__ unsigned ld4ic(const void* p) {
    unsigned r; asm volatile("global_load_dword %0, %1, off sc0 sc1" : "=v"(r) : "v"(p)); return r;
}
static __device__ __forceinline__ void st4ic(void* p, unsigned v) {
    asm volatile("global_store_dword %0, %1, off sc0 sc1" :: "v"(p), "v"(v) : "memory");
}
// non-temporal store: no LLC allocation (keeps scan working set resident)
static __device__ __forceinline__ void st4nt(void* p, float v) {
    asm volatile("global_store_dword %0, %1, off nt" :: "v"(p), "v"(v) : "memory");
}

// ---------------------------------------------------------------------------
__global__ void poison_hsbf(unsigned* __restrict__ p) {
    size_t i = (size_t)blockIdx.x * 256 + threadIdx.x;   // 524288 threads x 16B
    i32x4 v = { -1, -1, -1, -1 };
    asm volatile("global_store_dwordx4 %0, %1, off sc0 sc1"
                 :: "v"((char*)p + i * 16), "v"(v) : "memory");
}

// ---------------------------------------------------------------------------
__global__ void wt_convert(const float* __restrict__ W, unsigned short* __restrict__ Wt) {
    __shared__ float tile[32][33];
    int n0 = blockIdx.x * 32;
    int k0 = blockIdx.y * 32;
    int tx = threadIdx.x, ty = threadIdx.y;
    int n = n0 + tx;
    if (n < VOCAB) tile[ty][tx] = W[(size_t)(k0 + ty) * VOCAB + n];
    __syncthreads();
    int nn = n0 + ty;
    if (nn < VOCAB) Wt[(size_t)nn * HIDDEN + k0 + tx] = f32_to_bf16(tile[tx][ty]);
}

// ---------------------------------------------------------------------------
__global__ void wh_convert(const float* __restrict__ Whi, const float* __restrict__ Whf,
                           const float* __restrict__ Whc, const float* __restrict__ Who,
                           unsigned short* __restrict__ WhT) {
    __shared__ float tile[32][33];
    int g = blockIdx.z;
    const float* Wg = (g == 0) ? Whi : (g == 1) ? Whf : (g == 2) ? Whc : Who;
    int n0 = blockIdx.x * 32, k0 = blockIdx.y * 32;
    int tx = threadIdx.x, ty = threadIdx.y;
    tile[ty][tx] = Wg[(size_t)(k0 + ty) * HIDDEN + n0 + tx];
    __syncthreads();
    WhT[((size_t)g * HIDDEN + n0 + ty) * HIDDEN + k0 + tx] = f32_to_bf16(tile[tx][ty]);
}

// ---------------------------------------------------------------------------
__global__ __launch_bounds__(256) void xproj(
    const int* __restrict__ idx, const float* __restrict__ Emb,
    const float* __restrict__ Wxi, const float* __restrict__ Wxf,
    const float* __restrict__ Wxc, const float* __restrict__ Wxo,
    const float* __restrict__ bi,  const float* __restrict__ bf_,
    const float* __restrict__ bc,  const float* __restrict__ bo,
    float* __restrict__ xg)
{
    __shared__ float At[32][132];   // [k][m], padded
    __shared__ float Bt[32][68];    // [k][n], padded
    int cb = blockIdx.x;            // 0..31 (8 col-blocks per gate)
    int rb = blockIdx.y;            // 0..63
    int g  = cb >> 3;
    int hc0 = (cb & 7) * 64;
    const float* Wg = (g == 0) ? Wxi : (g == 1) ? Wxf : (g == 2) ? Wxc : Wxo;
    const float* bg = (g == 0) ? bi  : (g == 1) ? bf_ : (g == 2) ? bc  : bo;
    int m0 = rb * 128;
    int tid = threadIdx.x;
    int tr = tid >> 4, tc = tid & 15;
    float acc[8][4] = {};

    for (int kc = 0; kc < EMBED; kc += 32) {
        #pragma unroll
        for (int i = 0; i < 4; ++i) {
            int s = tid + i * 256;            // 0..1023
            int row = s >> 3, k4 = s & 7;
            int er = idx[m0 + row];
            f32x4 v = *reinterpret_cast<const f32x4*>(Emb + (size_t)er * EMBED + kc + k4 * 4);
            #pragma unroll
            for (int j = 0; j < 4; ++j) At[k4 * 4 + j][row] = v[j];
        }
        #pragma unroll
        for (int i = 0; i < 2; ++i) {
            int s = tid + i * 256;            // 0..511
            int k = s >> 4, c4 = s & 15;
            f32x4 v = *reinterpret_cast<const f32x4*>(Wg + (size_t)(kc + k) * HIDDEN + hc0 + c4 * 4);
            *reinterpret_cast<f32x4*>(&Bt[k][c4 * 4]) = v;
        }
        __syncthreads();
        #pragma unroll 8
        for (int k = 0; k < 32; ++k) {
            f32x4 a0 = *reinterpret_cast<const f32x4*>(&At[k][tr * 8]);
            f32x4 a1 = *reinterpret_cast<const f32x4*>(&At[k][tr * 8 + 4]);
            f32x4 b4 = *reinterpret_cast<const f32x4*>(&Bt[k][tc * 4]);
            float av[8] = {a0[0],a0[1],a0[2],a0[3],a1[0],a1[1],a1[2],a1[3]};
            #pragma unroll
            for (int i = 0; i < 8; ++i)
                #pragma unroll
                for (int j = 0; j < 4; ++j)
                    acc[i][j] += av[i] * b4[j];
        }
        __syncthreads();
    }
    f32x4 bb = *reinterpret_cast<const f32x4*>(bg + hc0 + tc * 4);
    #pragma unroll
    for (int i = 0; i < 8; ++i) {
        int row = m0 + tr * 8 + i;
        f32x4 o;
        #pragma unroll
        for (int j = 0; j < 4; ++j) o[j] = acc[i][j] + bb[j];
        *reinterpret_cast<f32x4*>(xg + (size_t)row * NGATE + g * HIDDEN + hc0 + tc * 4) = o;
    }
}

// ---------------------------------------------------------------------------
// FUSED persistent kernel, 256 blocks x 512 threads (cooperative):
//  blocks 0..31   : R8 batch-split double-pipeline LSTM scan (byte-identical).
//  blocks 32..255 : out_proj GEMM, m-tile OWNERSHIP: block owns one 128-row
//                   m-tile + n-range; A loaded ONCE into 64 VGPR/lane as MFMA
//                   fragments (canary gate + self-validating sentinel load);
//                   C written with nt (no LLC allocation).
// ---------------------------------------------------------------------------
__global__ __launch_bounds__(512) void lstm_fused(
    const float* __restrict__ xg,
    const unsigned short* __restrict__ WhT,   // [4][512][512] bf16
    unsigned short* hsbf,                     // [128][64][512] bf16 (poisoned)
    float* __restrict__ hfin, float* __restrict__ cfin,
    const unsigned short* __restrict__ Btbf,  // [10000][512] bf16
    const float* __restrict__ bias,           // [10000]
    float* __restrict__ Cout)                 // [8192][10000] f32
{
    __shared__ __align__(16) unsigned char smem[41472];
    const int tid = threadIdx.x;

    if (blockIdx.x < NBLK) {
        // =================== SCAN ROLE (R8, proven) ========================
        unsigned char* hstage = smem;                               // 32KB
        auto P_lds = reinterpret_cast<float (*)[32][17]>(smem + 32768);
        const int bx   = blockIdx.x;
        const int hc0  = bx * 16;
        const int lane = tid & 63, w = tid >> 6;
        const int wm   = w >> 2, wg = w & 3;

        bf16x8 breg[16];
        {
            const unsigned short* base =
                WhT + ((size_t)wg * HIDDEN + hc0 + (lane & 15)) * HIDDEN + (lane >> 4) * 8;
            #pragma unroll
            for (int ks = 0; ks < 16; ++ks)
                breg[ks] = *reinterpret_cast<const bf16x8*>(base + ks * 32);
        }

        const int ub  = tid >> 3;          // 0..31 (tid<256)
        const int uhp = tid & 7;
        const int uhc = hc0 + uhp * 2;
        float cA0 = 0.f, cA1 = 0.f, cB0 = 0.f, cB1 = 0.f;
        f32x2 xvA[4], xvB[4];
        if (tid < 256) {
            const float* xrA = xg + (size_t)(0 * 32 + ub) * NGATE + uhc;
            const float* xrB = xg + (size_t)(1 * 32 + ub) * NGATE + uhc;
            #pragma unroll
            for (int g = 0; g < 4; ++g) {
                xvA[g] = *reinterpret_cast<const f32x2*>(xrA + g * HIDDEN);
                xvB[g] = *reinterpret_cast<const f32x2*>(xrB + g * HIDDEN);
            }
        }
        unsigned* hs32 = reinterpret_cast<unsigned*>(hsbf);

#define CHK(R) { mx = (mx > (unsigned)R[0]) ? mx : (unsigned)R[0]; \
                 mx = (mx > (unsigned)R[1]) ? mx : (unsigned)R[1]; \
                 mx = (mx > (unsigned)R[2]) ? mx : (unsigned)R[2]; \
                 mx = (mx > (unsigned)R[3]) ? mx : (unsigned)R[3]; }
#define STLDS(R, I) { int s16 = (I) * 512 + tid; int row = s16 >> 6, sl = s16 & 63; \
        *reinterpret_cast<i32x4*>(hstage + row * 1024 + ((sl ^ (row & 7)) << 4)) = R; }

#define GROUP_UPDATE(G, XV, C0, C1, TT)                                         \
    if (tid < 256) {                                                            \
        int hp2 = uhp * 2;                                                      \
        float h0, h1;                                                           \
        cell2(P_lds[0][ub][hp2] + XV[0][0], P_lds[0][ub][hp2+1] + XV[0][1],     \
              P_lds[1][ub][hp2] + XV[1][0], P_lds[1][ub][hp2+1] + XV[1][1],     \
              P_lds[2][ub][hp2] + XV[2][0], P_lds[2][ub][hp2+1] + XV[2][1],     \
              P_lds[3][ub][hp2] + XV[3][0], P_lds[3][ub][hp2+1] + XV[3][1],     \
              C0, C1, h0, h1);                                                  \
        unsigned hp = ((unsigned)f32_to_bf16(h1) << 16) | (unsigned)f32_to_bf16(h0); \
        st4ic(hs32 + (size_t)(TT) * 16384 + ((G) * 32 + ub) * 256 + (uhc >> 1), hp); \
        if ((TT) == T_STEPS - 1) {                                              \
            f32x2 hv = { h0, h1 };                                              \
            *reinterpret_cast<f32x2*>(hfin + (size_t)((G) * 32 + ub) * HIDDEN + uhc) = hv; \
        } else {                                                                \
            const float* xr = xg + (size_t)(((TT) + 1) * BATCH + (G) * 32 + ub) * NGATE + uhc; \
            _Pragma("unroll")                                                   \
            for (int g = 0; g < 4; ++g)                                         \
                XV[g] = *reinterpret_cast<const f32x2*>(xr + g * HIDDEN);       \
        }                                                                       \
    }

#define GROUP_PHASE(G, XV, C0, C1, TT)                                          \
    {                                                                           \
        f32x4 acc = {0.f, 0.f, 0.f, 0.f};                                       \
        {                                                                       \
            const char* hb = (const char*)hsbf + (size_t)((TT) - 1) * 65536 + (G) * 32768; \
            i32x4 q0, q1, q2, q3;                                               \
            for (int rnd = 0; rnd < (1 << 16); ++rnd) {                         \
                q0 = ld16ic(hb + (size_t)(0 * 512 + tid) * 16);                 \
                q1 = ld16ic(hb + (size_t)(1 * 512 + tid) * 16);                 \
                q2 = ld16ic(hb + (size_t)(2 * 512 + tid) * 16);                 \
                q3 = ld16ic(hb + (size_t)(3 * 512 + tid) * 16);                 \
                asm volatile("s_waitcnt vmcnt(0)"                               \
                    : "+v"(q0), "+v"(q1), "+v"(q2), "+v"(q3));                  \
                unsigned mx = 0u;                                               \
                CHK(q0) CHK(q1) CHK(q2) CHK(q3)                                 \
                if (mx != 0xFFFFFFFFu) break;                                   \
                __builtin_amdgcn_s_sleep(1);                                    \
            }                                                                   \
            __builtin_amdgcn_sched_barrier(0);                                  \
            STLDS(q0, 0) STLDS(q1, 1) STLDS(q2, 2) STLDS(q3, 3)                 \
        }                                                                       \
        __syncthreads();                                                        \
        {                                                                       \
            const int rr = wm * 16 + (lane & 15);                               \
            _Pragma("unroll")                                                   \
            for (int ks = 0; ks < 16; ++ks) {                                   \
                int sl = ks * 4 + (lane >> 4);                                  \
                bf16x8 a = *reinterpret_cast<const bf16x8*>(                    \
                    hstage + rr * 1024 + ((sl ^ (rr & 7)) << 4));               \
                acc = __builtin_amdgcn_mfma_f32_16x16x32_bf16(a, breg[ks], acc, 0, 0, 0); \
            }                                                                   \
        }                                                                       \
        {                                                                       \
            int colr = lane & 15, rowb = (lane >> 4) * 4;                       \
            _Pragma("unroll")                                                   \
            for (int r = 0; r < 4; ++r)                                         \
                P_lds[wg][wm * 16 + rowb + r][colr] = acc[r];                   \
        }                                                                       \
        __syncthreads();                                                        \
        GROUP_UPDATE(G, XV, C0, C1, TT)                                         \
    }

        // t = 0: registers only
        if (tid < 256) {
            float h0, h1;
            cell2(xvA[0][0], xvA[0][1], xvA[1][0], xvA[1][1],
                  xvA[2][0], xvA[2][1], xvA[3][0], xvA[3][1], cA0, cA1, h0, h1);
            unsigned hp = ((unsigned)f32_to_bf16(h1) << 16) | (unsigned)f32_to_bf16(h0);
            st4ic(hs32 + (size_t)(0 * 32 + ub) * 256 + (uhc >> 1), hp);
            const float* xr = xg + (size_t)(1 * BATCH + 0 * 32 + ub) * NGATE + uhc;
            #pragma unroll
            for (int g = 0; g < 4; ++g)
                xvA[g] = *reinterpret_cast<const f32x2*>(xr + g * HIDDEN);

            cell2(xvB[0][0], xvB[0][1], xvB[1][0], xvB[1][1],
                  xvB[2][0], xvB[2][1], xvB[3][0], xvB[3][1], cB0, cB1, h0, h1);
            hp = ((unsigned)f32_to_bf16(h1) << 16) | (unsigned)f32_to_bf16(h0);
            st4ic(hs32 + (size_t)(1 * 32 + ub) * 256 + (uhc >> 1), hp);
            xr = xg + (size_t)(1 * BATCH + 1 * 32 + ub) * NGATE + uhc;
            #pragma unroll
            for (int g = 0; g < 4; ++g)
                xvB[g] = *reinterpret_cast<const f32x2*>(xr + g * HIDDEN);
        }

        for (int t = 1; t < T_STEPS; ++t) {
            GROUP_PHASE(0, xvA, cA0, cA1, t)
            GROUP_PHASE(1, xvB, cB0, cB1, t)
        }
#undef GROUP_PHASE
#undef GROUP_UPDATE
#undef STLDS
#undef CHK

        if (tid < 256) {
            f32x2 cvA = { cA0, cA1 };
            f32x2 cvB = { cB0, cB1 };
            *reinterpret_cast<f32x2*>(cfin + (size_t)(0 * 32 + ub) * HIDDEN + uhc) = cvA;
            *reinterpret_cast<f32x2*>(cfin + (size_t)(1 * 32 + ub) * HIDDEN + uhc) = cvB;
        }
    } else {
        // =================== GEMM ROLE (m-tile ownership) ==================
        char* sB = (char*)smem;                 // 80 rows x 128B = 10.25KB
        const int gbid = blockIdx.x - NBLK;     // 0..223
        const int w = tid >> 6, lane = tid & 63;

        int mi, k;
        if (gbid < 192) { mi = gbid / 3;        k = gbid % 3; }
        else            { int e = gbid - 192;   mi = 48 + (e >> 1); k = 3 + (e & 1); }
        int nstart, ncount;
        if (mi < 48) { nstart = (k < 2) ? k * 42 : 84; ncount = (k < 2) ? 42 : 41; }
        else         { nstart = k * 25;                ncount = 25; }

        // this lane's A-fragment row/addresses (rows w*16..w*16+15 per wave)
        const int r  = w * 16 + (lane & 15);          // 0..127 within m-tile
        const int tt = 2 * mi + (r >> 6);             // timestep
        const int bb_ = r & 63;                       // batch row
        const unsigned short* abase =
            hsbf + (size_t)(tt * BATCH + bb_) * HIDDEN + (lane >> 4) * 8;
        const unsigned short* cbase =
            hsbf + (size_t)(tt * BATCH + bb_) * HIDDEN + (w * 4 + (lane >> 4)) * 16;

        // ---- canary gate: 1 dword/lane (2KB/block/round), heavy backoff
        for (int rnd = 0; rnd < (1 << 20); ++rnd) {
            unsigned v = ld4ic(cbase);
            asm volatile("s_waitcnt vmcnt(0)" : "+v"(v));
            if (__syncthreads_count(v == 0xFFFFFFFFu) == 0) break;
            __builtin_amdgcn_s_sleep(32);
        }
        // ---- full self-validating A-frag load (R5 sentinel protocol)
        i32x4 areg[16];
        for (int rnd = 0; rnd < (1 << 16); ++rnd) {
            #pragma unroll
            for (int kcc = 0; kcc < 16; ++kcc)
                areg[kcc] = ld16ic((const char*)abase + kcc * 64);
            asm volatile("s_waitcnt vmcnt(0)" ::: "memory");
            __builtin_amdgcn_sched_barrier(0);
            unsigned mx = 0u;
            #pragma unroll
            for (int kcc = 0; kcc < 16; ++kcc)
                #pragma unroll
                for (int j = 0; j < 4; ++j)
                    mx = (mx > (unsigned)areg[kcc][j]) ? mx : (unsigned)areg[kcc][j];
            if (__syncthreads_count(mx == 0xFFFFFFFFu) == 0) break;
            __builtin_amdgcn_s_sleep(16);
        }

        // ---- n-tile loop: B staged per kc, A from registers, nt C-stores
        for (int nn = 0; nn < ncount; ++nn) {
            int n0 = (nstart + nn) * 80;
            f32x4 acc[5] = {};
            for (int kc = 0; kc < 8; ++kc) {
                int k0 = kc * 64;
                {
                    int s = tid, br = s >> 3, bs = s & 7;
                    i32x4 v = *reinterpret_cast<const i32x4*>(
                        Btbf + (size_t)(n0 + br) * HIDDEN + k0 + bs * 8);
                    *reinterpret_cast<i32x4*>(sB + br * 128 + ((bs ^ (br & 7)) * 16)) = v;
                    if (tid < 128) {
                        s = 512 + tid; br = s >> 3; bs = s & 7;
                        v = *reinterpret_cast<const i32x4*>(
                            Btbf + (size_t)(n0 + br) * HIDDEN + k0 + bs * 8);
                        *reinterpret_cast<i32x4*>(sB + br * 128 + ((bs ^ (br & 7)) * 16)) = v;
                    }
                }
                __syncthreads();
                #pragma unroll
                for (int k2 = 0; k2 < 2; ++k2) {
                    bf16x8 a = __builtin_bit_cast(bf16x8, areg[kc * 2 + k2]);
                    #pragma unroll
                    for (int cf = 0; cf < 5; ++cf) {
                        int brow = cf * 16 + (lane & 15);
                        int boff = (k2 * 64 + (lane >> 4) * 16) ^ ((brow & 7) << 4);
                        bf16x8 b = *reinterpret_cast<const bf16x8*>(sB + brow * 128 + boff);
                        acc[cf] = __builtin_amdgcn_mfma_f32_16x16x32_bf16(a, b, acc[cf], 0, 0, 0);
                    }
                }
                __syncthreads();
            }
            #pragma unroll
            for (int cf = 0; cf < 5; ++cf) {
                int col = n0 + cf * 16 + (lane & 15);
                float bv = bias[col];
                #pragma unroll
                for (int rr = 0; rr < 4; ++rr) {
                    int row = mi * 128 + w * 16 + (lane >> 4) * 4 + rr;
                    st4nt(&Cout[(size_t)row * VOCAB + col], acc[cf][rr] + bv);
                }
            }
        }
    }
}

// ---------------------------------------------------------------------------
__global__ void finalize_hc(const float* __restrict__ hfin, const float* __restrict__ cfin,
                            float* __restrict__ out) {
    int i = blockIdx.x * 256 + threadIdx.x;       // 0..65535
    size_t base = (size_t)M_ROWS * VOCAB;
    if (i < BATCH * HIDDEN)
        out[base + i] = hfin[i];
    else
        out[base + i] = cfin[i - BATCH * HIDDEN];
}

extern "C" void kernel_launch(void* const* d_in, const int* in_sizes, int n_in,
                              void* d_out, int out_size, void* d_ws, size_t ws_size,
                              hipStream_t stream) {
    (void)in_sizes; (void)n_in; (void)out_size; (void)ws_size;
    const int*   input_ = (const int*)  d_in[0];
    const float* Emb    = (const float*)d_in[1];
    const float* Wxi    = (const float*)d_in[2];
    const float* Whi    = (const float*)d_in[3];
    const float* bi     = (const float*)d_in[4];
    const float* Wxf    = (const float*)d_in[5];
    const float* Whf    = (const float*)d_in[6];
    const float* bf_    = (const float*)d_in[7];
    const float* Wxc    = (const float*)d_in[8];
    const float* Whc    = (const float*)d_in[9];
    const float* bc     = (const float*)d_in[10];
    const float* Wxo    = (const float*)d_in[11];
    const float* Who    = (const float*)d_in[12];
    const float* bo     = (const float*)d_in[13];
    const float* W      = (const float*)d_in[14];
    const float* b      = (const float*)d_in[15];
    float* out = (float*)d_out;

    char* ws = (char*)d_ws;
    float*          xg   = (float*)         (ws);                 // 67,108,864
    unsigned short* hsbf = (unsigned short*)(ws +  67108864);     //  8,388,608
    unsigned short* Wtbf = (unsigned short*)(ws +  75497472);     // 10,240,000
    unsigned short* WhT  = (unsigned short*)(ws +  85737472);     //  2,097,152
    float*          hfin = (float*)         (ws +  87834624);     //    131,072
    float*          cbuf = (float*)         (ws +  87965696);     //    131,072

    poison_hsbf<<<2048, 256, 0, stream>>>((unsigned*)hsbf);
    wt_convert<<<dim3(313, 16), dim3(32, 32), 0, stream>>>(W, Wtbf);
    wh_convert<<<dim3(16, 16, 4), dim3(32, 32), 0, stream>>>(Whi, Whf, Whc, Who, WhT);
    xproj<<<dim3(32, 64), 256, 0, stream>>>(input_, Emb, Wxi, Wxf, Wxc, Wxo,
                                            bi, bf_, bc, bo, xg);

    {
        const float* xg_c = xg;
        const unsigned short* WhT_c = WhT;
        unsigned short* hsbf_p = hsbf;
        float* hfin_p = hfin; float* cbuf_p = cbuf;
        const unsigned short* Wtbf_c = Wtbf;
        const float* b_c = b;
        float* out_p = out;
        void* args[] = { (void*)&xg_c, (void*)&WhT_c, (void*)&hsbf_p,
                         (void*)&hfin_p, (void*)&cbuf_p,
                         (void*)&Wtbf_c, (void*)&b_c, (void*)&out_p };
        hipLaunchCooperativeKernel((void*)lstm_fused, dim3(NLAUNCH), dim3(512), args, 0, stream);
    }

    finalize_hc<<<256, 256, 0, stream>>>(hfin, cbuf, out);
}